// Round 5
// baseline (83.252 us; speedup 1.0000x reference)
//
#include <hip/hip_runtime.h>

#define BATCH 10000
#define NCH 64
#define DIM_IN 16
#define DIM_OUT 99   // floats per row per channel-block: 99*64 = 6336

typedef float f32x4 __attribute__((ext_vector_type(4)));

// ---------------- compile-time CG construction (C++17 constexpr) ----------------
namespace cgc {

struct cx { double re; double im; };

constexpr cx cmul(cx a, cx b) {
    return cx{a.re * b.re - a.im * b.im, a.re * b.im + a.im * b.re};
}

constexpr double cfact(int n) {
    double r = 1.0;
    for (int i = 2; i <= n; ++i) r *= (double)i;
    return r;
}

constexpr double csqrt(double x) {
    if (x <= 0.0) return 0.0;
    double y = x > 1.0 ? x : 1.0;
    for (int i = 0; i < 100; ++i) y = 0.5 * (y + x / y);
    return y;
}

constexpr int imax(int a, int b) { return a > b ? a : b; }
constexpr int imin(int a, int b) { return a < b ? a : b; }
constexpr int iabs(int a) { return a < 0 ? -a : a; }

// Racah formula (exact ratios of factorials <= 10! in double)
constexpr double su2_cg(int j1, int m1, int j2, int m2, int j3, int m3) {
    if (m3 != m1 + m2) return 0.0;
    if (j3 < iabs(j1 - j2) || j3 > j1 + j2) return 0.0;
    int vmin = imax(imax(-j1 + j2 + m3, -j1 + m1), 0);
    int vmax = imin(imin(j2 + j3 + m1, j3 - j1 + j2), j3 + m3);
    double C = (2.0 * j3 + 1.0) *
        (cfact(j3 + j1 - j2) * cfact(j3 - j1 + j2) * cfact(j1 + j2 - j3) *
         cfact(j3 + m3) * cfact(j3 - m3)) /
        (cfact(j1 + j2 + j3 + 1) * cfact(j1 - m1) * cfact(j1 + m1) *
         cfact(j2 - m2) * cfact(j2 + m2));
    double S = 0.0;
    for (int v = vmin; v <= vmax; ++v) {
        double t = (cfact(j2 + j3 + m1 - v) * cfact(j1 - m1 + v)) /
                   (cfact(v) * cfact(j3 - j1 + j2 - v) * cfact(j3 + m3 - v) *
                    cfact(v + j1 - j2 - m3));
        S += ((v + j2 + m2) & 1) ? -t : t;
    }
    return csqrt(C) * S;
}

// real SH -> complex SH basis change (matches e3nn, incl. (-i)^l phase)
constexpr void fill_q(int l, cx* q) {
    const int n = 2 * l + 1;
    const double is2 = 0.70710678118654752440;
    for (int e = 0; e < n * n; ++e) q[e] = cx{0.0, 0.0};
    for (int m = -l; m < 0; ++m) {
        q[(l + m) * n + (l - m)] = cx{is2, 0.0};
        q[(l + m) * n + (l + m)] = cx{0.0, -is2};
    }
    q[l * n + l] = cx{1.0, 0.0};
    for (int m = 1; m <= l; ++m) {
        double s = (m & 1) ? -1.0 : 1.0;
        q[(l + m) * n + (l + m)] = cx{s * is2, 0.0};
        q[(l + m) * n + (l - m)] = cx{0.0, s * is2};
    }
    cx ph = (l & 3) == 0 ? cx{1.0, 0.0}
          : (l & 3) == 1 ? cx{0.0, -1.0}
          : (l & 3) == 2 ? cx{-1.0, 0.0}
                         : cx{0.0, 1.0};
    for (int e = 0; e < n * n; ++e) q[e] = cmul(ph, q[e]);
}

template<int l1, int l2, int l3>
struct InstCG { float v[(2 * l1 + 1) * (2 * l2 + 1) * (2 * l3 + 1)]; };

// real-basis wigner_3j * sqrt(2*l3+1), unit Frobenius norm before scaling
template<int l1, int l2, int l3>
constexpr InstCG<l1, l2, l3> make_inst() {
    constexpr int n1 = 2 * l1 + 1, n2 = 2 * l2 + 1, n3 = 2 * l3 + 1;
    double C[n1 * n2 * n3] = {};
    for (int i = 0; i < n1; ++i)
        for (int k = 0; k < n2; ++k)
            for (int nn = 0; nn < n3; ++nn)
                C[(i * n2 + k) * n3 + nn] = su2_cg(l1, i - l1, l2, k - l2, l3, nn - l3);
    cx Q1[n1 * n1] = {}; cx Q2[n2 * n2] = {}; cx Q3[n3 * n3] = {};
    fill_q(l1, Q1); fill_q(l2, Q2); fill_q(l3, Q3);
    double R[n1 * n2 * n3] = {};
    double ss = 0.0;
    for (int j = 0; j < n1; ++j)
        for (int lc = 0; lc < n2; ++lc)
            for (int m = 0; m < n3; ++m) {
                double ar = 0.0;
                for (int i = 0; i < n1; ++i) {
                    cx q1 = Q1[i * n1 + j];
                    if (q1.re == 0.0 && q1.im == 0.0) continue;
                    for (int k = 0; k < n2; ++k) {
                        cx q12 = cmul(q1, Q2[k * n2 + lc]);
                        if (q12.re == 0.0 && q12.im == 0.0) continue;
                        for (int nn = 0; nn < n3; ++nn) {
                            double cc = C[(i * n2 + k) * n3 + nn];
                            if (cc == 0.0) continue;
                            cx q3 = Q3[nn * n3 + m];
                            ar += (q12.re * q3.re + q12.im * q3.im) * cc;
                        }
                    }
                }
                R[(j * n2 + lc) * n3 + m] = ar;
                ss += ar * ar;
            }
    double scale = csqrt((double)n3) / csqrt(ss);
    InstCG<l1, l2, l3> T{};
    for (int e = 0; e < n1 * n2 * n3; ++e) T.v[e] = (float)(R[e] * scale);
    return T;
}

}  // namespace cgc

// One instruction: accumulate its n3 slots and ds_write each (1 KB/slot/wave)
// into the wave's LDS ring at ring[slot&15][row][ch].
template<int l1, int l2, int l3, int o2, int o3>
__device__ __forceinline__ void do_inst(const f32x4* xbl, const f32x4* yv,
                                        float* ringw, int lane) {
    constexpr int n1 = 2 * l1 + 1, n2 = 2 * l2 + 1, n3 = 2 * l3 + 1;
    constexpr cgc::InstCG<l1, l2, l3> T = cgc::make_inst<l1, l2, l3>();
    f32x4 acc[n3];
#pragma unroll
    for (int m3 = 0; m3 < n3; ++m3) acc[m3] = (f32x4)0.0f;
#pragma unroll
    for (int m1 = 0; m1 < n1; ++m1) {
#pragma unroll
        for (int m2 = 0; m2 < n2; ++m2) {
            const f32x4 p = xbl[m1] * yv[o2 + m2];
#pragma unroll
            for (int m3 = 0; m3 < n3; ++m3) {
                const float c = T.v[(m1 * n2 + m2) * n3 + m3];
                if (c != 0.0f) acc[m3] += c * p;
            }
        }
    }
    const int wbase = ((lane >> 4) << 6) + ((lane & 15) << 2);  // row*64 + cq*4
#pragma unroll
    for (int m3 = 0; m3 < n3; ++m3) {
        constexpr int dummy = 0; (void)dummy;
        *reinterpret_cast<f32x4*>(&ringw[(((o3 + m3) & 15) << 8) + wbase]) = acc[m3];
    }
}

// Flush slots [4k, 4k+4): 4 store instructions, each 1 KB fully contiguous
// covering one batch row, ascending addresses. Normal cached stores.
__device__ __forceinline__ void flush4(const float* ringw, int k, float* __restrict__ out,
                                       int b0, int lane) {
    const int sl = 4 * k + (lane >> 4);            // slot this lane serves
    const int src = ((sl & 15) << 8) + ((lane & 15) << 2);
#pragma unroll
    for (int r = 0; r < 4; ++r) {
        const f32x4 v = *reinterpret_cast<const f32x4*>(&ringw[src + (r << 6)]);
        *reinterpret_cast<f32x4*>(&out[(size_t)(b0 + r) * (DIM_OUT * NCH)
                                       + (sl << 6) + ((lane & 15) << 2)]) = v;
    }
}

// 128-thread blocks (2 waves). Wave covers 4 batch rows (16 lanes each).
// y fully resident (64 VGPR); x streamed per l1-group (<=28 VGPR).
// Instructions in ascending-o3 order (== l1-major), slots complete densely
// 0..98; 16-deep LDS ring per wave; flush 4 slots -> 4x 1KB contiguous stores.
__global__ __launch_bounds__(128, 3) void tp_main(const float* __restrict__ x,
                                                  const float* __restrict__ y,
                                                  float* __restrict__ out) {
    __shared__ float ring[2][16][4][64];   // 32 KB: [wave][slot%16][row][ch]

    const int tid = threadIdx.x;
    const int wid = tid >> 6;
    const int lane = tid & 63;
    const int g = blockIdx.x * 128 + tid;
    const int b = g >> 4;                 // this thread's batch row
    const int cl = g & 15;                // channel quad
    const int b0 = b - (lane >> 4);       // wave's first batch row

    float* ringw = &ring[wid][0][0][0];

    const f32x4* x4 = reinterpret_cast<const f32x4*>(x + (size_t)b * (DIM_IN * NCH)) + cl;
    const f32x4* y4 = reinterpret_cast<const f32x4*>(y + (size_t)b * (DIM_IN * NCH)) + cl;

    f32x4 yv[DIM_IN];
#pragma unroll
    for (int i = 0; i < DIM_IN; ++i) yv[i] = y4[i * 16];

    // ---- l1 = 0 : x row 0 ----
    {
        f32x4 xbl[1];
        xbl[0] = x4[0 * 16];
        do_inst<0,0,0, 0,0>(xbl, yv, ringw, lane);                       // slots 0
        do_inst<0,1,1, 1,1>(xbl, yv, ringw, lane);                       // 1-3
        flush4(ringw, 0, out, b0, lane);
        do_inst<0,2,2, 4,4>(xbl, yv, ringw, lane);                       // 4-8
        flush4(ringw, 1, out, b0, lane);
        do_inst<0,3,3, 9,9>(xbl, yv, ringw, lane);                       // 9-15
        flush4(ringw, 2, out, b0, lane);
        flush4(ringw, 3, out, b0, lane);
    }
    // ---- l1 = 1 : x rows 1..3 ----
    {
        f32x4 xbl[3];
#pragma unroll
        for (int i = 0; i < 3; ++i) xbl[i] = x4[(1 + i) * 16];
        do_inst<1,0,1, 0,16>(xbl, yv, ringw, lane);                      // 16-18
        do_inst<1,1,0, 1,19>(xbl, yv, ringw, lane);                      // 19
        flush4(ringw, 4, out, b0, lane);
        do_inst<1,1,2, 1,20>(xbl, yv, ringw, lane);                      // 20-24
        flush4(ringw, 5, out, b0, lane);
        do_inst<1,2,1, 4,25>(xbl, yv, ringw, lane);                      // 25-27
        flush4(ringw, 6, out, b0, lane);
        do_inst<1,2,3, 4,28>(xbl, yv, ringw, lane);                      // 28-34
        flush4(ringw, 7, out, b0, lane);
        do_inst<1,3,2, 9,35>(xbl, yv, ringw, lane);                      // 35-39
        flush4(ringw, 8, out, b0, lane);
        flush4(ringw, 9, out, b0, lane);
    }
    // ---- l1 = 2 : x rows 4..8 ----
    {
        f32x4 xbl[5];
#pragma unroll
        for (int i = 0; i < 5; ++i) xbl[i] = x4[(4 + i) * 16];
        do_inst<2,0,2, 0,40>(xbl, yv, ringw, lane);                      // 40-44
        flush4(ringw, 10, out, b0, lane);
        do_inst<2,1,1, 1,45>(xbl, yv, ringw, lane);                      // 45-47
        flush4(ringw, 11, out, b0, lane);
        do_inst<2,1,3, 1,48>(xbl, yv, ringw, lane);                      // 48-54
        flush4(ringw, 12, out, b0, lane);
        do_inst<2,2,0, 4,55>(xbl, yv, ringw, lane);                      // 55
        flush4(ringw, 13, out, b0, lane);
        do_inst<2,2,2, 4,56>(xbl, yv, ringw, lane);                      // 56-60
        flush4(ringw, 14, out, b0, lane);
        do_inst<2,3,1, 9,61>(xbl, yv, ringw, lane);                      // 61-63
        flush4(ringw, 15, out, b0, lane);
        do_inst<2,3,3, 9,64>(xbl, yv, ringw, lane);                      // 64-70
        flush4(ringw, 16, out, b0, lane);
    }
    // ---- l1 = 3 : x rows 9..15 ----
    {
        f32x4 xbl[7];
#pragma unroll
        for (int i = 0; i < 7; ++i) xbl[i] = x4[(9 + i) * 16];
        do_inst<3,0,3, 0,71>(xbl, yv, ringw, lane);                      // 71-77
        flush4(ringw, 17, out, b0, lane);
        flush4(ringw, 18, out, b0, lane);
        do_inst<3,1,2, 1,78>(xbl, yv, ringw, lane);                      // 78-82
        flush4(ringw, 19, out, b0, lane);
        do_inst<3,2,1, 4,83>(xbl, yv, ringw, lane);                      // 83-85
        flush4(ringw, 20, out, b0, lane);
        do_inst<3,2,3, 4,86>(xbl, yv, ringw, lane);                      // 86-92
        flush4(ringw, 21, out, b0, lane);
        flush4(ringw, 22, out, b0, lane);
        do_inst<3,3,0, 9,93>(xbl, yv, ringw, lane);                      // 93
        do_inst<3,3,2, 9,94>(xbl, yv, ringw, lane);                      // 94-98
        flush4(ringw, 23, out, b0, lane);
        // tail: slots 96-98 (3 slots, lanes 0-47)
        if (lane < 48) {
            const int sl = 96 + (lane >> 4);
            const int src = ((sl & 15) << 8) + ((lane & 15) << 2);
#pragma unroll
            for (int r = 0; r < 4; ++r) {
                const f32x4 v = *reinterpret_cast<const f32x4*>(&ringw[src + (r << 6)]);
                *reinterpret_cast<f32x4*>(&out[(size_t)(b0 + r) * (DIM_OUT * NCH)
                                               + (sl << 6) + ((lane & 15) << 2)]) = v;
            }
        }
    }
}

extern "C" void kernel_launch(void* const* d_in, const int* in_sizes, int n_in,
                              void* d_out, int out_size, void* d_ws, size_t ws_size,
                              hipStream_t stream) {
    const float* x = (const float*)d_in[0];
    const float* y = (const float*)d_in[1];
    float* out = (float*)d_out;
    hipLaunchKernelGGL(tp_main, dim3(BATCH * 16 / 128), dim3(128), 0, stream,
                       x, y, out);
}